// Round 3
// baseline (1898.140 us; speedup 1.0000x reference)
//
#include <hip/hip_runtime.h>

// RealNVP forward, fused across all 8 coupling layers.  Round 11.
// B=131072, D=64, H=256, L=8. out = y[B*D] ++ logdet[B], fp32.
//
// Evidence through R10: pipe-busy totals invariant (MFMA ~180us, VALU
// ~400us, LDS ~370us) while wall sits at ~975-985; R9 proved thin phases
// are fatal; R8 vs R10 proved barrier-count and occupancy trade ~1:1 at a
// 4-wave sync domain.  Binding constraint: phase-aligned stall -- every
// barrier aligns 4 waves, and 2-3 resident blocks can't cover the drains.
//
// R11: shrink the SYNC DOMAIN, keep phase fatness and occupancy.
//  - Block = 128 threads (2 waves), BM=32 rows; each wave owns an H-HALF
//    (128 rows = 8 m-tiles).  Per-wave phase work identical to R8 (mm2 =
//    128 MFMA, eps = 16 cells) -- the proven-fat shape.
//  - __syncthreads aligns only 2 waves; LDS 21504 B -> 6-7 blocks/CU, so
//    ~12 waves/CU of INDEPENDENT blocks cover each other's drains.
//  - serial nets (one act buffer) -- R10 showed intra-block pipe pairing
//    adds nothing over cross-block wave overlap.
//  - bias folded into acc init (replaces zero-init, kills bias adds in
//    every epilogue).
//  - cost: per-wave weight traffic 2x (H/2 not H/4) -> ~12.6 GB L2 over
//    the kernel (~365us L2 service), overlappable; weights stay L2-hot.
// Everything else = R8/R10: transposed matmuls, padded linear LDS
// (ACT_S 264, XM_S 72 -> 2-way-alias-free patterns), pk4 packing,
// tanh_fast, fp16 weights in ws, s3 in registers.

#define BATCH    131072
#define DIM      64
#define HID      256
#define NLAYER   8
#define BM       32
#define NTHREADS 128

#define ACT_S 264   // act row stride, halfs (256 + 8)
#define XM_S  72    // xm  row stride, halfs (64 + 8)

typedef _Float16 f16;
typedef __attribute__((ext_vector_type(8))) _Float16 f16x8;
typedef __attribute__((ext_vector_type(4))) _Float16 f16x4;
typedef __attribute__((ext_vector_type(2))) _Float16 f16x2;
typedef __attribute__((ext_vector_type(4))) float    f32x4;

#define TWO_LOG2E 2.8853900817779268f   // 2*log2(e)
#define LOG2E     1.4426950408889634f

__device__ __forceinline__ float tanh_fast(float x) {
  // tanh(x) = 1 - 2/(e^{2x}+1); exact +-1 limits at inf -> no clamps needed.
  float e = __builtin_amdgcn_exp2f(x * TWO_LOG2E);
  return 1.f - 2.f * __builtin_amdgcn_rcpf(e + 1.f);
}

// Pack 4 f32 -> f16x4 with two v_cvt_pkrtz_f16_f32.
__device__ __forceinline__ f16x4 pk4(float a, float b, float c, float d) {
  f16x2 lo = __builtin_bit_cast(f16x2, __builtin_amdgcn_cvt_pkrtz(a, b));
  f16x2 hi = __builtin_bit_cast(f16x2, __builtin_amdgcn_cvt_pkrtz(c, d));
  f16x4 o; o[0] = lo[0]; o[1] = lo[1]; o[2] = hi[0]; o[3] = hi[1];
  return o;
}

__device__ __forceinline__ f32x4 bias4(const float* __restrict__ p) {
  const float4 v = *(const float4*)p;
  f32x4 o; o[0] = v.x; o[1] = v.y; o[2] = v.z; o[3] = v.w;
  return o;
}

// fp32 -> fp16 weight pack, all 6 tensors in one launch.
__global__ void cvt6_kernel(const float* s0, f16* d0, const float* s1, f16* d1,
                            const float* s2, f16* d2, const float* s3, f16* d3,
                            const float* s4, f16* d4, const float* s5, f16* d5) {
  // quad counts: 32768, 131072, 32768, 32768, 131072, 32768 (total 393216)
  int i = blockIdx.x * blockDim.x + threadIdx.x;
  const float* s; f16* d; int base;
  if      (i < 32768)  { s = s0; d = d0; base = 0; }
  else if (i < 163840) { s = s1; d = d1; base = 32768; }
  else if (i < 196608) { s = s2; d = d2; base = 163840; }
  else if (i < 229376) { s = s3; d = d3; base = 196608; }
  else if (i < 360448) { s = s4; d = d4; base = 229376; }
  else                 { s = s5; d = d5; base = 360448; }
  int k = i - base;
  float4 v = ((const float4*)s)[k];
  ((f16x4*)d)[k] = pk4(v.x, v.y, v.z, v.w);
}

__global__ __launch_bounds__(NTHREADS, 3) void flow_kernel(
    const float* __restrict__ x, const float* __restrict__ masks,
    const f16* __restrict__ wS1, const f16* __restrict__ wS2, const f16* __restrict__ wS3,
    const float* __restrict__ sb1, const float* __restrict__ sb2, const float* __restrict__ sb3,
    const float* __restrict__ scl,
    const f16* __restrict__ wT1, const f16* __restrict__ wT2, const f16* __restrict__ wT3,
    const float* __restrict__ tb1, const float* __restrict__ tb2, const float* __restrict__ tb3,
    float* __restrict__ y_out, float* __restrict__ ld_out)
{
  __shared__ __attribute__((aligned(16))) f16 act [BM * ACT_S];   // 16896 B
  __shared__ __attribute__((aligned(16))) f16 xm_s[BM * XM_S];    //  4608 B
  float* ld_red = (float*)xm_s;  // aliased: xm dead by the time logdet reduces

  const int tid   = threadIdx.x;
  const int lane  = tid & 63;
  const int wv    = tid >> 6;        // wave 0..1: H-half (mm1/mm2), D-half (mm3)
  const int quad  = lane >> 4;
  const int l16   = lane & 15;
  const int row0  = blockIdx.x * BM;
  const int hbase = wv * 128;        // this wave's hidden rows [hbase, hbase+128)
  const int dbase = wv * 32;         // this wave's D rows [dbase, dbase+32)

  // Per-lane state: batch row = n*16+l16 (n=0..1), D = dbase+m3*16+quad*4+r.
  float yv [2][2][4];   // [m3][n][r] flow state, fp32
  float s3r[2][2][4];   // s-net output, kept in regs across the two nets
  float lda[2];         // logdet accumulator per n
  #pragma unroll
  for (int m3 = 0; m3 < 2; ++m3)
    #pragma unroll
    for (int n = 0; n < 2; ++n) {
      const float4 v = *(const float4*)
          &x[(size_t)(row0 + n * 16 + l16) * DIM + dbase + m3 * 16 + quad * 4];
      yv[m3][n][0] = v.x; yv[m3][n][1] = v.y; yv[m3][n][2] = v.z; yv[m3][n][3] = v.w;
    }
  lda[0] = 0.f; lda[1] = 0.f;

  // layer-0 mask + xm
  float4 mv0 = *(const float4*)&masks[dbase +      quad * 4];
  float4 mv1 = *(const float4*)&masks[dbase + 16 + quad * 4];
  #pragma unroll
  for (int n = 0; n < 2; ++n) {
    *(f16x4*)&xm_s[(n * 16 + l16) * XM_S + dbase + quad * 4] =
        pk4(yv[0][n][0] * mv0.x, yv[0][n][1] * mv0.y,
            yv[0][n][2] * mv0.z, yv[0][n][3] * mv0.w);
    *(f16x4*)&xm_s[(n * 16 + l16) * XM_S + dbase + 16 + quad * 4] =
        pk4(yv[1][n][0] * mv1.x, yv[1][n][1] * mv1.y,
            yv[1][n][2] * mv1.z, yv[1][n][3] * mv1.w);
  }
  __syncthreads();                                     // xm ready

  #pragma unroll 1
  for (int l = 0; l < NLAYER; ++l) {
    #pragma unroll 1
    for (int net = 0; net < 2; ++net) {
      const f16*   W1 = (net ? wT1 : wS1) + l * HID * DIM;
      const f16*   W2 = (net ? wT2 : wS2) + l * HID * HID;
      const f16*   W3 = (net ? wT3 : wS3) + l * DIM * HID;
      const float* b1 = (net ? tb1 : sb1) + l * HID;
      const float* b2 = (net ? tb2 : sb2) + l * HID;
      const float* b3 = (net ? tb3 : sb3) + l * DIM;

      f32x4 acc[8][2];   // [m = hidden tile (this wave's half)][n = batch tile]

      // ---- mm1 (transposed): C[h, b] = W1 @ xm^T, acc init = bias ----
      #pragma unroll
      for (int m = 0; m < 8; ++m) {
        const f32x4 bi = bias4(&b1[hbase + m * 16 + quad * 4]);
        acc[m][0] = bi; acc[m][1] = bi;
      }
      #pragma unroll
      for (int kt = 0; kt < 2; ++kt) {
        const int k0 = kt * 32 + quad * 8;
        f16x8 afr[8];
        #pragma unroll
        for (int m = 0; m < 8; ++m)
          afr[m] = *(const f16x8*)&W1[(hbase + m * 16 + l16) * DIM + k0];
        #pragma unroll
        for (int n = 0; n < 2; ++n) {
          const f16x8 bfr = *(const f16x8*)&xm_s[(n * 16 + l16) * XM_S + k0];
          #pragma unroll
          for (int m = 0; m < 8; ++m)
            acc[m][n] = __builtin_amdgcn_mfma_f32_16x16x32_f16(afr[m], bfr, acc[m][n], 0, 0, 0);
        }
      }
      // ep1: act[b, h..h+3] = tanh(acc) (bias already inside)
      #pragma unroll
      for (int m = 0; m < 8; ++m) {
        const int h0 = hbase + m * 16 + quad * 4;
        #pragma unroll
        for (int n = 0; n < 2; ++n)
          *(f16x4*)&act[(n * 16 + l16) * ACT_S + h0] =
              pk4(tanh_fast(acc[m][n][0]), tanh_fast(acc[m][n][1]),
                  tanh_fast(acc[m][n][2]), tanh_fast(acc[m][n][3]));
      }
      __syncthreads();                                 // h1 ready (both halves)

      // ---- mm2 (transposed): W2 @ h1^T, residual tanh ----
      #pragma unroll
      for (int m = 0; m < 8; ++m) {
        const f32x4 bi = bias4(&b2[hbase + m * 16 + quad * 4]);
        acc[m][0] = bi; acc[m][1] = bi;
      }
      #pragma unroll 1
      for (int kt = 0; kt < 8; ++kt) {
        const int k0 = kt * 32 + quad * 8;
        f16x8 afr[8];
        #pragma unroll
        for (int m = 0; m < 8; ++m)
          afr[m] = *(const f16x8*)&W2[(hbase + m * 16 + l16) * HID + k0];
        #pragma unroll
        for (int n = 0; n < 2; ++n) {
          const f16x8 bfr = *(const f16x8*)&act[(n * 16 + l16) * ACT_S + k0];
          #pragma unroll
          for (int m = 0; m < 8; ++m)
            acc[m][n] = __builtin_amdgcn_mfma_f32_16x16x32_f16(afr[m], bfr, acc[m][n], 0, 0, 0);
        }
      }
      __syncthreads();                                 // all done reading act
      #pragma unroll
      for (int m = 0; m < 8; ++m) {
        const int h0 = hbase + m * 16 + quad * 4;
        #pragma unroll
        for (int n = 0; n < 2; ++n) {
          f16x4* p = (f16x4*)&act[(n * 16 + l16) * ACT_S + h0];
          const f16x4 prev = *p;                       // own cell (same lane wrote it)
          *p = pk4(tanh_fast(acc[m][n][0] + (float)prev[0]),
                   tanh_fast(acc[m][n][1] + (float)prev[1]),
                   tanh_fast(acc[m][n][2] + (float)prev[2]),
                   tanh_fast(acc[m][n][3] + (float)prev[3]));
        }
      }
      __syncthreads();                                 // h2 ready

      // ---- mm3 (transposed): W3 @ h2^T -> C[D, b], acc init = b3 ----
      f32x4 acc3[2][2];  // [m3][n]
      #pragma unroll
      for (int m3 = 0; m3 < 2; ++m3) {
        const f32x4 bi = bias4(&b3[dbase + m3 * 16 + quad * 4]);
        acc3[m3][0] = bi; acc3[m3][1] = bi;
      }
      #pragma unroll 2
      for (int kt = 0; kt < 8; ++kt) {
        const int k0 = kt * 32 + quad * 8;
        const f16x8 a0 = *(const f16x8*)&W3[(dbase +      l16) * HID + k0];
        const f16x8 a1 = *(const f16x8*)&W3[(dbase + 16 + l16) * HID + k0];
        #pragma unroll
        for (int n = 0; n < 2; ++n) {
          const f16x8 bfr = *(const f16x8*)&act[(n * 16 + l16) * ACT_S + k0];
          acc3[0][n] = __builtin_amdgcn_mfma_f32_16x16x32_f16(a0, bfr, acc3[0][n], 0, 0, 0);
          acc3[1][n] = __builtin_amdgcn_mfma_f32_16x16x32_f16(a1, bfr, acc3[1][n], 0, 0, 0);
        }
      }
      if (net == 0) __syncthreads();   // act free for t-net's ep1
      // t-net's post-mm3 path is guarded by the layer-bottom barrier

      if (net == 0) {
        const float4 sv0 = *(const float4*)&scl[l * DIM + dbase +      quad * 4];
        const float4 sv1 = *(const float4*)&scl[l * DIM + dbase + 16 + quad * 4];
        // s3 stays in registers: same lane owns (d,b) in both nets.
        #define S3C(m3, n, r, SC, MC) \
          s3r[m3][n][r] = (tanh_fast(acc3[m3][n][r]) + yv[m3][n][r] * (MC)) * (SC);
        #pragma unroll
        for (int n = 0; n < 2; ++n) {
          S3C(0, n, 0, sv0.x, mv0.x) S3C(0, n, 1, sv0.y, mv0.y)
          S3C(0, n, 2, sv0.z, mv0.z) S3C(0, n, 3, sv0.w, mv0.w)
          S3C(1, n, 0, sv1.x, mv1.x) S3C(1, n, 1, sv1.y, mv1.y)
          S3C(1, n, 2, sv1.z, mv1.z) S3C(1, n, 3, sv1.w, mv1.w)
        }
        #undef S3C
      } else {
        // ep3-t: named scalars only (nothing demotable to scratch).
        #define EP3T(m3, n, r, MC) {                                     \
          const float y0 = yv[m3][n][r];                                 \
          const float s  = s3r[m3][n][r];                                \
          const float om = 1.f - (MC);                                   \
          const float tv = acc3[m3][n][r] + y0 * (MC);                   \
          const float e  = __builtin_amdgcn_exp2f(s * LOG2E);            \
          yv[m3][n][r] = (MC) * y0 + om * (y0 * e + tv);                 \
          lda[n] += om * s; }
        #pragma unroll
        for (int n = 0; n < 2; ++n) {
          EP3T(0, n, 0, mv0.x) EP3T(0, n, 1, mv0.y)
          EP3T(0, n, 2, mv0.z) EP3T(0, n, 3, mv0.w)
          EP3T(1, n, 0, mv1.x) EP3T(1, n, 1, mv1.y)
          EP3T(1, n, 2, mv1.z) EP3T(1, n, 3, mv1.w)
        }
        #undef EP3T
      }
    } // net

    if (l + 1 < NLAYER) {
      mv0 = *(const float4*)&masks[(l + 1) * DIM + dbase +      quad * 4];
      mv1 = *(const float4*)&masks[(l + 1) * DIM + dbase + 16 + quad * 4];
      #pragma unroll
      for (int n = 0; n < 2; ++n) {
        *(f16x4*)&xm_s[(n * 16 + l16) * XM_S + dbase + quad * 4] =
            pk4(yv[0][n][0] * mv0.x, yv[0][n][1] * mv0.y,
                yv[0][n][2] * mv0.z, yv[0][n][3] * mv0.w);
        *(f16x4*)&xm_s[(n * 16 + l16) * XM_S + dbase + 16 + quad * 4] =
            pk4(yv[1][n][0] * mv1.x, yv[1][n][1] * mv1.y,
                yv[1][n][2] * mv1.z, yv[1][n][3] * mv1.w);
      }
    }
    __syncthreads();              // xm ready / final: pre-reduction fence
  } // layers

  // y out: coalesced dwordx4 per (m3, n)
  #pragma unroll
  for (int m3 = 0; m3 < 2; ++m3)
    #pragma unroll
    for (int n = 0; n < 2; ++n) {
      float4 v;
      v.x = yv[m3][n][0]; v.y = yv[m3][n][1];
      v.z = yv[m3][n][2]; v.w = yv[m3][n][3];
      *(float4*)&y_out[(size_t)(row0 + n * 16 + l16) * DIM + dbase + m3 * 16 + quad * 4] = v;
    }

  // logdet: lda[n] = this lane's partial (its 8 d-values of row n*16+l16);
  // reduce over quads (shfl), then across the 2 waves via LDS.
  float v0 = lda[0], v1 = lda[1];
  v0 += __shfl_xor(v0, 16); v0 += __shfl_xor(v0, 32);
  v1 += __shfl_xor(v1, 16); v1 += __shfl_xor(v1, 32);
  if (quad == 0) {
    ld_red[(0 * 16 + l16) * 2 + wv] = v0;
    ld_red[(1 * 16 + l16) * 2 + wv] = v1;
  }
  __syncthreads();
  if (tid < BM)
    ld_out[row0 + tid] = ld_red[tid * 2 + 0] + ld_red[tid * 2 + 1];
}

extern "C" void kernel_launch(void* const* d_in, const int* in_sizes, int n_in,
                              void* d_out, int out_size, void* d_ws, size_t ws_size,
                              hipStream_t stream) {
  const float* x     = (const float*)d_in[0];
  const float* masks = (const float*)d_in[1];
  const float* sW1f  = (const float*)d_in[2];
  const float* sb1   = (const float*)d_in[3];
  const float* sW2f  = (const float*)d_in[4];
  const float* sb2   = (const float*)d_in[5];
  const float* sW3f  = (const float*)d_in[6];
  const float* sb3   = (const float*)d_in[7];
  const float* scl   = (const float*)d_in[8];
  const float* tW1f  = (const float*)d_in[9];
  const float* tb1   = (const float*)d_in[10];
  const float* tW2f  = (const float*)d_in[11];
  const float* tb2   = (const float*)d_in[12];
  const float* tW3f  = (const float*)d_in[13];
  const float* tb3   = (const float*)d_in[14];
  (void)in_sizes; (void)n_in; (void)out_size; (void)ws_size;

  const int W1SZ = NLAYER * HID * DIM;   // 131072
  const int W2SZ = NLAYER * HID * HID;   // 524288
  const int W3SZ = NLAYER * DIM * HID;   // 131072
  f16* wS1 = (f16*)d_ws;
  f16* wS2 = wS1 + W1SZ;
  f16* wS3 = wS2 + W2SZ;
  f16* wT1 = wS3 + W3SZ;
  f16* wT2 = wT1 + W1SZ;
  f16* wT3 = wT2 + W2SZ;

  // total float4 quads = 393216 -> 1536 blocks x 256
  cvt6_kernel<<<1536, 256, 0, stream>>>(sW1f, wS1, sW2f, wS2, sW3f, wS3,
                                        tW1f, wT1, tW2f, wT2, tW3f, wT3);

  float* y_out  = (float*)d_out;
  float* ld_out = y_out + (size_t)BATCH * DIM;
  flow_kernel<<<BATCH / BM, NTHREADS, 0, stream>>>(
      x, masks, wS1, wS2, wS3, sb1, sb2, sb3, scl,
      wT1, wT2, wT3, tb1, tb2, tb3, y_out, ld_out);
}